// Round 1
// baseline (542.100 us; speedup 1.0000x reference)
//
#include <hip/hip_runtime.h>

constexpr int LAYERS = 24;
constexpr int DIM    = 2048;
constexpr int NBLK   = 8;
constexpr int BSZ    = 3;            // layers per block (24/8, rem 0)
constexpr float EPSV = 1e-6f;
constexpr int TPB    = 256;
constexpr int EPT    = DIM / TPB;    // 8 elements per thread

__global__ void __launch_bounds__(TPB)
block_attn_res_kernel(const float* __restrict__ lo,   // (L, B*T, D)
                      const float* __restrict__ emb,  // (B*T, D)
                      const float* __restrict__ qry,  // (L, D)
                      const float* __restrict__ wgt,  // (D)
                      float* __restrict__ out,        // (L, B*T, D)
                      int bt_total)
{
    const int bt   = blockIdx.x;
    const int tid  = threadIdx.x;
    const int lane = tid & 63;
    const int wid  = tid >> 6;
    const int d0   = tid * EPT;

    __shared__ float red[4][12];

    // ---- load embedding slice and weight slice (stay in regs whole kernel)
    float e[EPT], wt[EPT];
    #pragma unroll
    for (int j = 0; j < EPT; j += 4) {
        float4 v = *reinterpret_cast<const float4*>(emb + (size_t)bt * DIM + d0 + j);
        e[j] = v.x; e[j+1] = v.y; e[j+2] = v.z; e[j+3] = v.w;
        float4 u = *reinterpret_cast<const float4*>(wgt + d0 + j);
        wt[j] = u.x; wt[j+1] = u.y; wt[j+2] = u.z; wt[j+3] = u.w;
    }

    float S[NBLK-1][EPT];     // finished block sums S_0..S_6 (S_7 never used)
    float part[EPT];          // running within-block partial sum
    float ssq_emb;
    float ssq_S[NBLK-1];

    // ---- sum-of-squares of emb (once)
    {
        float v = 0.f;
        #pragma unroll
        for (int j = 0; j < EPT; ++j) v += e[j] * e[j];
        #pragma unroll
        for (int off = 32; off; off >>= 1) v += __shfl_xor(v, off);
        if (lane == 0) red[wid][0] = v;
        __syncthreads();
        ssq_emb = red[0][0] + red[1][0] + red[2][0] + red[3][0];
        __syncthreads();
    }

    const float invD = 1.f / (float)DIM;

    #pragma unroll
    for (int l = 0; l < LAYERS; ++l) {
        const int m    = l / BSZ;               // block index (compile-time)
        const int i    = l - m * BSZ;           // within-block offset
        const int nsrc = 1 + m + (i > 0 ? 1 : 0);

        // ---- load q_l*w and f_l early (overlap with reductions)
        float qw[EPT], f[EPT];
        #pragma unroll
        for (int j = 0; j < EPT; j += 4) {
            float4 v = *reinterpret_cast<const float4*>(qry + (size_t)l * DIM + d0 + j);
            qw[j] = v.x * wt[j]; qw[j+1] = v.y * wt[j+1];
            qw[j+2] = v.z * wt[j+2]; qw[j+3] = v.w * wt[j+3];
            float4 u = *reinterpret_cast<const float4*>(
                lo + ((size_t)l * bt_total + bt) * DIM + d0 + j);
            f[j] = u.x; f[j+1] = u.y; f[j+2] = u.z; f[j+3] = u.w;
        }

        // ---- per-thread partial dots (+ sumsq of the changing source)
        float vals[11];
        int nv = 0;
        {
            float dv = 0.f;
            #pragma unroll
            for (int j = 0; j < EPT; ++j) dv += e[j] * qw[j];
            vals[nv++] = dv;
        }
        #pragma unroll
        for (int s = 0; s < m; ++s) {
            float dv = 0.f;
            #pragma unroll
            for (int j = 0; j < EPT; ++j) dv += S[s][j] * qw[j];
            vals[nv++] = dv;
        }
        if (i > 0) {
            float dv = 0.f, sq = 0.f;
            #pragma unroll
            for (int j = 0; j < EPT; ++j) { dv += part[j] * qw[j]; sq += part[j] * part[j]; }
            vals[nv++] = dv;
            vals[nv++] = sq;                    // sumsq of partial (changes every layer)
        } else if (m > 0) {
            float sq = 0.f;                     // lazily finalize sumsq of S_{m-1}
            #pragma unroll
            for (int j = 0; j < EPT; ++j) sq += S[m-1][j] * S[m-1][j];
            vals[nv++] = sq;
        }

        // ---- batched block-wide reduction (wave shfl tree + 4-wave LDS join)
        #pragma unroll
        for (int v = 0; v < nv; ++v) {
            float x = vals[v];
            #pragma unroll
            for (int off = 32; off; off >>= 1) x += __shfl_xor(x, off);
            if (lane == 0) red[wid][v] = x;
        }
        __syncthreads();
        #pragma unroll
        for (int v = 0; v < nv; ++v)
            vals[v] = red[0][v] + red[1][v] + red[2][v] + red[3][v];
        __syncthreads();

        if (i == 0 && m > 0) ssq_S[m-1] = vals[nsrc];
        const float ssq_part = (i > 0) ? vals[nsrc] : 0.f;

        // ---- scores = dot(v, q*w) * rsqrt(mean(v^2)+eps)
        float scr[NBLK+1];
        scr[0] = vals[0] * rsqrtf(ssq_emb * invD + EPSV);
        #pragma unroll
        for (int s = 0; s < m; ++s)
            scr[1+s] = vals[1+s] * rsqrtf(ssq_S[s] * invD + EPSV);
        if (i > 0)
            scr[m+1] = vals[m+1] * rsqrtf(ssq_part * invD + EPSV);

        // ---- softmax over nsrc (replicated scalar work, n<=9)
        float mx = scr[0];
        #pragma unroll
        for (int s = 1; s < nsrc; ++s) mx = fmaxf(mx, scr[s]);
        float al[NBLK+1];
        float den = 0.f;
        #pragma unroll
        for (int s = 0; s < nsrc; ++s) { al[s] = __expf(scr[s] - mx); den += al[s]; }
        const float inv = 1.f / den;

        // ---- h = sum_j alpha_j * v_j
        float h[EPT];
        {
            const float a = al[0] * inv;
            #pragma unroll
            for (int j = 0; j < EPT; ++j) h[j] = a * e[j];
        }
        #pragma unroll
        for (int s = 0; s < m; ++s) {
            const float a = al[1+s] * inv;
            #pragma unroll
            for (int j = 0; j < EPT; ++j) h[j] += a * S[s][j];
        }
        if (i > 0) {
            const float a = al[m+1] * inv;
            #pragma unroll
            for (int j = 0; j < EPT; ++j) h[j] += a * part[j];
        }

        // ---- store output slice
        #pragma unroll
        for (int j = 0; j < EPT; j += 4) {
            float4 v; v.x = h[j]; v.y = h[j+1]; v.z = h[j+2]; v.w = h[j+3];
            *reinterpret_cast<float4*>(
                out + ((size_t)l * bt_total + bt) * DIM + d0 + j) = v;
        }

        // ---- advance partial / finalize block sum
        if (i == 0) {
            #pragma unroll
            for (int j = 0; j < EPT; ++j) part[j] = f[j];
        } else {
            #pragma unroll
            for (int j = 0; j < EPT; ++j) part[j] += f[j];
        }
        if (i == BSZ - 1 && m < NBLK - 1) {
            #pragma unroll
            for (int j = 0; j < EPT; ++j) S[m][j] = part[j];
        }
    }
}

extern "C" void kernel_launch(void* const* d_in, const int* in_sizes, int n_in,
                              void* d_out, int out_size, void* d_ws, size_t ws_size,
                              hipStream_t stream) {
    const float* lo  = (const float*)d_in[0];  // layer_outputs (L,B,T,D)
    const float* emb = (const float*)d_in[1];  // embedding (B,T,D)
    const float* qry = (const float*)d_in[2];  // queries (L,D)
    const float* wgt = (const float*)d_in[3];  // key_norm_weight (D)
    float* outp = (float*)d_out;

    const int bt_total = in_sizes[1] / DIM;    // B*T = 2048

    hipLaunchKernelGGL(block_attn_res_kernel,
                       dim3(bt_total), dim3(TPB), 0, stream,
                       lo, emb, qry, wgt, outp, bt_total);
}

// Round 3
// 525.499 us; speedup vs baseline: 1.0316x; 1.0316x over previous
//
#include <hip/hip_runtime.h>
#include <hip/hip_bf16.h>

constexpr int LAYERS = 24;
constexpr int DIM    = 2048;
constexpr int NBLK   = 8;
constexpr int BSZ    = 3;            // 24/8, remainder 0
constexpr float EPSV = 1e-6f;
constexpr int TPB    = 256;
constexpr int EPT    = 8;            // elements per thread
constexpr int HALF   = 1024;

typedef float vf4 __attribute__((ext_vector_type(4)));

// element j (0..7) of thread t lives at global d-index: (j>>2)*HALF + 4*t + (j&3)
// -> every 16B access is lane-contiguous (perfect 1KB/wave coalescing)

__device__ __forceinline__ unsigned pk2(float a, float b) {
    __hip_bfloat162 h2(__float2bfloat16(a), __float2bfloat16(b));
    union { __hip_bfloat162 h; unsigned u; } c; c.h = h2; return c.u;
}
__device__ __forceinline__ float upk(unsigned p, int hi) {
    union { unsigned u; float f; } c;
    c.u = hi ? (p & 0xffff0000u) : (p << 16);
    return c.f;
}

__global__ void prep_qw_kernel(const float* __restrict__ q,
                               const float* __restrict__ w,
                               float* __restrict__ qw, int n) {
    int idx = blockIdx.x * blockDim.x + threadIdx.x;
    if (idx < n) qw[idx] = q[idx] * w[idx & (DIM - 1)];
}

template<bool PREMUL>
__global__ void __launch_bounds__(TPB, 4)
block_attn_res_kernel(const float* __restrict__ lo,   // (L, B*T, D)
                      const float* __restrict__ emb,  // (B*T, D)
                      const float* __restrict__ q1,   // premultiplied q*w (L,D) or raw q
                      const float* __restrict__ wgt,  // (D) -- only if !PREMUL
                      float* __restrict__ out,        // (L, B*T, D)
                      int bt_total)
{
    const int bt   = blockIdx.x;
    const int tid  = threadIdx.x;
    const int lane = tid & 63;
    const int wid  = tid >> 6;
    const int c0   = tid * 4;

    __shared__ float red[2][4][12];

    // ---- embedding slice (f32, registers for whole kernel)
    float e[EPT];
    {
        const float* ep = emb + (size_t)bt * DIM;
        vf4 v0 = __builtin_nontemporal_load(reinterpret_cast<const vf4*>(ep + c0));
        vf4 v1 = __builtin_nontemporal_load(reinterpret_cast<const vf4*>(ep + HALF + c0));
        e[0]=v0.x; e[1]=v0.y; e[2]=v0.z; e[3]=v0.w;
        e[4]=v1.x; e[5]=v1.y; e[6]=v1.z; e[7]=v1.w;
    }

    unsigned Spk[NBLK-1][EPT/2];   // finished block sums, packed bf16x2
    float part[EPT];               // running within-block partial (f32)
    float ssq_S[NBLK-1];
    float ssq_emb;

    // ---- sumsq(emb) once (uses red[0]; safe: red[0] next written at layer 2,
    //      which is after layer 1's barrier)
    {
        float v = 0.f;
        #pragma unroll
        for (int j = 0; j < EPT; ++j) v += e[j] * e[j];
        #pragma unroll
        for (int off = 32; off; off >>= 1) v += __shfl_xor(v, off);
        if (lane == 0) red[0][wid][0] = v;
        __syncthreads();
        ssq_emb = red[0][0][0] + red[0][1][0] + red[0][2][0] + red[0][3][0];
    }
    const float invD = 1.f / (float)DIM;

    #pragma unroll
    for (int l = 0; l < LAYERS; ++l) {
        const int m    = l / BSZ;
        const int i    = l - m * BSZ;
        const int nsrc = 1 + m + (i > 0 ? 1 : 0);

        // ---- f_l slice (streamed, read-once)
        float f[EPT];
        {
            const float* fp = lo + ((size_t)l * bt_total + bt) * DIM;
            vf4 u0 = __builtin_nontemporal_load(reinterpret_cast<const vf4*>(fp + c0));
            vf4 u1 = __builtin_nontemporal_load(reinterpret_cast<const vf4*>(fp + HALF + c0));
            f[0]=u0.x; f[1]=u0.y; f[2]=u0.z; f[3]=u0.w;
            f[4]=u1.x; f[5]=u1.y; f[6]=u1.z; f[7]=u1.w;
        }

        if (l == 0) {
            // single source -> softmax == 1 -> h = emb
            float* op = out + ((size_t)l * bt_total + bt) * DIM;
            vf4 w0; w0.x=e[0]; w0.y=e[1]; w0.z=e[2]; w0.w=e[3];
            vf4 w1; w1.x=e[4]; w1.y=e[5]; w1.z=e[6]; w1.w=e[7];
            __builtin_nontemporal_store(w0, reinterpret_cast<vf4*>(op + c0));
            __builtin_nontemporal_store(w1, reinterpret_cast<vf4*>(op + HALF + c0));
            #pragma unroll
            for (int j = 0; j < EPT; ++j) part[j] = f[j];
            continue;
        }

        // ---- q_l * w slice
        float qwv[EPT];
        {
            const float* qp = q1 + (size_t)l * DIM;
            vf4 v0 = *reinterpret_cast<const vf4*>(qp + c0);
            vf4 v1 = *reinterpret_cast<const vf4*>(qp + HALF + c0);
            qwv[0]=v0.x; qwv[1]=v0.y; qwv[2]=v0.z; qwv[3]=v0.w;
            qwv[4]=v1.x; qwv[5]=v1.y; qwv[6]=v1.z; qwv[7]=v1.w;
            if (!PREMUL) {
                vf4 w0 = *reinterpret_cast<const vf4*>(wgt + c0);
                vf4 w1 = *reinterpret_cast<const vf4*>(wgt + HALF + c0);
                qwv[0]*=w0.x; qwv[1]*=w0.y; qwv[2]*=w0.z; qwv[3]*=w0.w;
                qwv[4]*=w1.x; qwv[5]*=w1.y; qwv[6]*=w1.z; qwv[7]*=w1.w;
            }
        }

        // ---- per-thread partial dots (+ the one changing sumsq)
        float vals[11];
        int nv = 0;
        {
            float dv = 0.f;
            #pragma unroll
            for (int j = 0; j < EPT; ++j) dv += e[j] * qwv[j];
            vals[nv++] = dv;
        }
        #pragma unroll
        for (int s = 0; s < m; ++s) {
            float dv = 0.f;
            #pragma unroll
            for (int j = 0; j < EPT; ++j) dv += upk(Spk[s][j >> 1], j & 1) * qwv[j];
            vals[nv++] = dv;
        }
        if (i > 0) {
            float dv = 0.f, sq = 0.f;
            #pragma unroll
            for (int j = 0; j < EPT; ++j) { dv += part[j] * qwv[j]; sq += part[j] * part[j]; }
            vals[nv++] = dv;
            vals[nv++] = sq;
        } else {            // i==0, m>=1: finalize sumsq of S_{m-1} (bf16-consistent)
            float sq = 0.f;
            #pragma unroll
            for (int j = 0; j < EPT; ++j) {
                float sv = upk(Spk[m-1][j >> 1], j & 1);
                sq += sv * sv;
            }
            vals[nv++] = sq;
        }

        // ---- block reduction: wave shfl tree + 4-wave LDS join, ONE barrier
        const int p = l & 1;
        #pragma unroll
        for (int v = 0; v < nv; ++v) {
            float x = vals[v];
            #pragma unroll
            for (int off = 32; off; off >>= 1) x += __shfl_xor(x, off);
            if (lane == 0) red[p][wid][v] = x;
        }
        __syncthreads();
        #pragma unroll
        for (int v = 0; v < nv; ++v)
            vals[v] = red[p][0][v] + red[p][1][v] + red[p][2][v] + red[p][3][v];
        // (no trailing barrier: red[p] is next overwritten two layers later,
        //  strictly after the intervening layer's barrier)

        if (i == 0) ssq_S[m-1] = vals[nsrc];
        const float ssq_part = (i > 0) ? vals[nsrc] : 0.f;

        // ---- scores
        float scr[NBLK + 1];
        scr[0] = vals[0] * rsqrtf(ssq_emb * invD + EPSV);
        #pragma unroll
        for (int s = 0; s < m; ++s)
            scr[1+s] = vals[1+s] * rsqrtf(ssq_S[s] * invD + EPSV);
        if (i > 0)
            scr[m+1] = vals[m+1] * rsqrtf(ssq_part * invD + EPSV);

        // ---- softmax over nsrc (<=9, replicated)
        float mx = scr[0];
        #pragma unroll
        for (int s = 1; s < nsrc; ++s) mx = fmaxf(mx, scr[s]);
        float al[NBLK + 1];
        float den = 0.f;
        #pragma unroll
        for (int s = 0; s < nsrc; ++s) { al[s] = __expf(scr[s] - mx); den += al[s]; }
        const float inv = 1.f / den;

        // ---- h = sum_s alpha_s * v_s
        float h[EPT];
        {
            const float a = al[0] * inv;
            #pragma unroll
            for (int j = 0; j < EPT; ++j) h[j] = a * e[j];
        }
        #pragma unroll
        for (int s = 0; s < m; ++s) {
            const float a = al[1+s] * inv;
            #pragma unroll
            for (int j = 0; j < EPT; ++j) h[j] += a * upk(Spk[s][j >> 1], j & 1);
        }
        if (i > 0) {
            const float a = al[m+1] * inv;
            #pragma unroll
            for (int j = 0; j < EPT; ++j) h[j] += a * part[j];
        }

        // ---- store
        {
            float* op = out + ((size_t)l * bt_total + bt) * DIM;
            vf4 w0; w0.x=h[0]; w0.y=h[1]; w0.z=h[2]; w0.w=h[3];
            vf4 w1; w1.x=h[4]; w1.y=h[5]; w1.z=h[6]; w1.w=h[7];
            __builtin_nontemporal_store(w0, reinterpret_cast<vf4*>(op + c0));
            __builtin_nontemporal_store(w1, reinterpret_cast<vf4*>(op + HALF + c0));
        }

        // ---- advance partial / finalize block sum (packed bf16)
        if (i == 0) {
            #pragma unroll
            for (int j = 0; j < EPT; ++j) part[j] = f[j];
        } else {
            #pragma unroll
            for (int j = 0; j < EPT; ++j) part[j] += f[j];
        }
        if (i == BSZ - 1 && m < NBLK - 1) {
            #pragma unroll
            for (int j2 = 0; j2 < EPT/2; ++j2)
                Spk[m][j2] = pk2(part[2*j2], part[2*j2 + 1]);
        }
    }
}

extern "C" void kernel_launch(void* const* d_in, const int* in_sizes, int n_in,
                              void* d_out, int out_size, void* d_ws, size_t ws_size,
                              hipStream_t stream) {
    const float* lo  = (const float*)d_in[0];  // layer_outputs (L,B,T,D)
    const float* emb = (const float*)d_in[1];  // embedding (B,T,D)
    const float* qry = (const float*)d_in[2];  // queries (L,D)
    const float* wgt = (const float*)d_in[3];  // key_norm_weight (D)
    float* outp = (float*)d_out;

    const int bt_total = in_sizes[1] / DIM;    // B*T
    const int nq = in_sizes[2];                // L*D

    if (ws_size >= (size_t)nq * sizeof(float)) {
        float* qwbuf = (float*)d_ws;
        prep_qw_kernel<<<(nq + TPB - 1) / TPB, TPB, 0, stream>>>(qry, wgt, qwbuf, nq);
        block_attn_res_kernel<true><<<bt_total, TPB, 0, stream>>>(
            lo, emb, qwbuf, nullptr, outp, bt_total);
    } else {
        block_attn_res_kernel<false><<<bt_total, TPB, 0, stream>>>(
            lo, emb, qry, wgt, outp, bt_total);
    }
}